// Round 3
// baseline (125.938 us; speedup 1.0000x reference)
//
#include <hip/hip_runtime.h>

#define BATCH 16384
#define NF    512
#define DEG   8
#define NC    10
#define KB    8

#define SPLITF 8
#define FC     (NF / SPLITF)     // 64 features per block
#define RB     128               // rows per block
#define PITCH  68                // 64+4: rows 16B-aligned (68%4==0), bank phase 4
#define NT     256               // 4 waves; each wave owns 2x 16-row MFMA tiles
#define NWAVES 4

typedef __attribute__((ext_vector_type(8))) short bfrag;   // 8 bf16 (4 VGPRs)
typedef __attribute__((ext_vector_type(4))) float f32x4;   // MFMA C/D

union frag_u { bfrag s; unsigned u[4]; };

__device__ __forceinline__ float fast_tanh(float x) {
    float e = __expf(2.0f * x);
    return 1.0f - 2.0f * __builtin_amdgcn_rcpf(e + 1.0f);
}
__device__ __forceinline__ float fast_sigmoid(float x) {
    return __builtin_amdgcn_rcpf(1.0f + __expf(-x));
}
// round-half-away f32->bf16, two at once: 2 adds + 1 v_perm
__device__ __forceinline__ unsigned bfpack2(float lo, float hi) {
    unsigned ul = __builtin_bit_cast(unsigned, lo) + 0x8000u;
    unsigned uh = __builtin_bit_cast(unsigned, hi) + 0x8000u;
    return __builtin_amdgcn_perm(uh, ul, 0x07060302);
}
// T_1..T_8 of s, packed as MFMA A-fragment (element j = T_{j+1})
__device__ __forceinline__ bfrag cheb_frag(float s) {
    float T[KB];
    float tkm1 = 1.0f, tk = s;
    const float s2 = 2.0f * s;
#pragma unroll
    for (int k = 0; k < KB; ++k) {
        T[k] = tk;
        float tn = fmaf(s2, tk, -tkm1);
        tkm1 = tk; tk = tn;
    }
    frag_u f;
#pragma unroll
    for (int i = 0; i < 4; ++i) f.u[i] = bfpack2(T[2 * i], T[2 * i + 1]);
    return f.s;
}

// out[b][c] = bias[c]  (d_out is poisoned before every launch)
__global__ __launch_bounds__(256) void init_out(const float* __restrict__ bias,
                                                float* __restrict__ out) {
    int i = blockIdx.x * 256 + threadIdx.x;
    if (i < BATCH * NC) out[i] = bias[i % NC];
}

__global__ __launch_bounds__(NT, 4) void qkan_kernel(
    const float* __restrict__ X,        // (B, F)
    const float* __restrict__ lcu_w,    // (F, DEG)
    const float* __restrict__ alpha,    // (F, DEG)
    const float* __restrict__ coeff,    // (C, F, KB)
    const float* __restrict__ base,     // (C, F)
    float* __restrict__ out)            // (B, C), pre-filled with bias
{
    __shared__ float s_mem[RB * PITCH];   // 34.8 KB: summed(b,f) tile

    const int t      = threadIdx.x;
    const int rowblk = blockIdx.x >> 3;
    const int fsplit = blockIdx.x & (SPLITF - 1);
    const int row0   = rowblk * RB;
    const int fbase  = fsplit * FC;

    // ---------------- phase 1: elementwise -> summed(b,f) into LDS ----------
    {
        const int f2   = t & 31;      // feature pair fA, fA+1
        const int rsub = t >> 5;      // 0..7
        const int fA   = fbase + f2 * 2;

        float w[2][DEG], a[2][DEG], rden[2];   // row-invariant, hoisted
#pragma unroll
        for (int i = 0; i < 2; ++i) {
            const float4 w0 = *(const float4*)(lcu_w + (fA + i) * DEG);
            const float4 w1 = *(const float4*)(lcu_w + (fA + i) * DEG + 4);
            const float4 a0 = *(const float4*)(alpha + (fA + i) * DEG);
            const float4 a1 = *(const float4*)(alpha + (fA + i) * DEG + 4);
            w[i][0]=w0.x; w[i][1]=w0.y; w[i][2]=w0.z; w[i][3]=w0.w;
            w[i][4]=w1.x; w[i][5]=w1.y; w[i][6]=w1.z; w[i][7]=w1.w;
            a[i][0]=a0.x; a[i][1]=a0.y; a[i][2]=a0.z; a[i][3]=a0.w;
            a[i][4]=a1.x; a[i][5]=a1.y; a[i][6]=a1.z; a[i][7]=a1.w;
            float den = 1e-8f;
#pragma unroll
            for (int d = 0; d < DEG; ++d) den += fabsf(w[i][d]);
            rden[i] = __builtin_amdgcn_rcpf(den);
        }

#pragma unroll
        for (int it = 0; it < RB / 8; ++it) {
            const int r = rsub + it * 8;
            const float2 xv = *(const float2*)(X + (row0 + r) * NF + fA);
            float xs[2] = {xv.x, xv.y};
            float sums[2];
#pragma unroll
            for (int i = 0; i < 2; ++i) {
                const float x  = 0.99f * fast_tanh(xs[i]);
                const float x2 = 2.0f * x;
                float tkm1 = 1.0f, tk = x, num = 0.0f;
#pragma unroll
                for (int d = 0; d < DEG; ++d) {
                    num = fmaf(w[i][d], tk, num);
                    float tn = fmaf(x2, tk, -tkm1);
                    tkm1 = tk; tk = tn;
                }
                const float lcu = num * rden[i];
                float ss = 0.0f;
#pragma unroll
                for (int d = 0; d < DEG; ++d)
                    ss += __sinf(lcu * a[i][d]);
                sums[i] = 0.125f * ss;
            }
            *(float2*)(&s_mem[r * PITCH + f2 * 2]) = make_float2(sums[0], sums[1]);
        }
    }
    __syncthreads();

    // ------------- phase 2: MFMA contraction --------------------------------
    // GEMM1: phi (RB x FC*8 bf16) @ coeff^T (FC*8 x 16)  -> 16 K-tiles/wave-tile
    // GEMM2: silu (RB x FC bf16) @ base^T  (FC x 16)     -> 2 K-tiles/wave-tile
    const int lane = t & 63;
    const int wave = __builtin_amdgcn_readfirstlane(t >> 6);
    const int n    = lane & 15;          // class col (A-row m for A frags)
    const int q    = lane >> 4;          // quad
    const bool nv  = (n < NC);
    const int  ncl = nv ? n : (NC - 1);  // clamp for always-valid loads

    // B fragments, built once per block (bf16). B[k][n]: n=lane&15, k=q*8+j.
    bfrag Bc[16];
#pragma unroll
    for (int kt = 0; kt < 16; ++kt) {
        const float* p = coeff + (ncl * NF + fbase + kt * 4 + q) * KB;
        float4 c0 = *(const float4*)p;
        float4 c1 = *(const float4*)(p + 4);
        if (!nv) { c0 = make_float4(0,0,0,0); c1 = make_float4(0,0,0,0); }
        frag_u f;
        f.u[0] = bfpack2(c0.x, c0.y); f.u[1] = bfpack2(c0.z, c0.w);
        f.u[2] = bfpack2(c1.x, c1.y); f.u[3] = bfpack2(c1.z, c1.w);
        Bc[kt] = f.s;
    }
    bfrag Bs[2];
#pragma unroll
    for (int kt2 = 0; kt2 < 2; ++kt2) {
        const float* p = base + ncl * NF + fbase + kt2 * 32 + q * 8;
        float4 b0 = *(const float4*)p;
        float4 b1 = *(const float4*)(p + 4);
        if (!nv) { b0 = make_float4(0,0,0,0); b1 = make_float4(0,0,0,0); }
        frag_u f;
        f.u[0] = bfpack2(b0.x, b0.y); f.u[1] = bfpack2(b0.z, b0.w);
        f.u[2] = bfpack2(b1.x, b1.y); f.u[3] = bfpack2(b1.z, b1.w);
        Bs[kt2] = f.s;
    }

    const int r_l0 = wave * 32 + n;        // A-row for tile 0 (m = lane&15)
    const int r_l1 = r_l0 + 16;            // tile 1

    f32x4 acc0 = {0.f, 0.f, 0.f, 0.f};
    f32x4 acc1 = {0.f, 0.f, 0.f, 0.f};

#pragma unroll
    for (int kt = 0; kt < 16; ++kt) {
        const int fl = kt * 4 + q;         // this lane's feature for this K-tile
        const float s0 = s_mem[r_l0 * PITCH + fl];
        const float s1 = s_mem[r_l1 * PITCH + fl];
        const bfrag a0 = cheb_frag(0.99f * fast_tanh(s0));
        const bfrag a1 = cheb_frag(0.99f * fast_tanh(s1));
        acc0 = __builtin_amdgcn_mfma_f32_16x16x32_bf16(a0, Bc[kt], acc0, 0, 0, 0);
        acc1 = __builtin_amdgcn_mfma_f32_16x16x32_bf16(a1, Bc[kt], acc1, 0, 0, 0);
    }

#pragma unroll
    for (int kt2 = 0; kt2 < 2; ++kt2) {
        const int off = kt2 * 32 + q * 8;
#pragma unroll
        for (int tt = 0; tt < 2; ++tt) {
            const int rl = (tt == 0) ? r_l0 : r_l1;
            const float4 v0 = *(const float4*)(&s_mem[rl * PITCH + off]);
            const float4 v1 = *(const float4*)(&s_mem[rl * PITCH + off + 4]);
            float v[8] = {v0.x, v0.y, v0.z, v0.w, v1.x, v1.y, v1.z, v1.w};
            float sl[8];
#pragma unroll
            for (int j = 0; j < 8; ++j)
                sl[j] = v[j] * fast_sigmoid(v[j]);
            frag_u f;
            f.u[0] = bfpack2(sl[0], sl[1]); f.u[1] = bfpack2(sl[2], sl[3]);
            f.u[2] = bfpack2(sl[4], sl[5]); f.u[3] = bfpack2(sl[6], sl[7]);
            if (tt == 0)
                acc0 = __builtin_amdgcn_mfma_f32_16x16x32_bf16(f.s, Bs[kt2], acc0, 0, 0, 0);
            else
                acc1 = __builtin_amdgcn_mfma_f32_16x16x32_bf16(f.s, Bs[kt2], acc1, 0, 0, 0);
        }
    }

    // ------------- epilogue: D row = q*4+i, col = n ------------------------
    if (nv) {
#pragma unroll
        for (int i = 0; i < 4; ++i) {
            const int rg0 = row0 + wave * 32 + q * 4 + i;
            unsafeAtomicAdd(out + rg0 * NC + n, acc0[i]);
            unsafeAtomicAdd(out + (rg0 + 16) * NC + n, acc1[i]);
        }
    }
}

extern "C" void kernel_launch(void* const* d_in, const int* in_sizes, int n_in,
                              void* d_out, int out_size, void* d_ws, size_t ws_size,
                              hipStream_t stream) {
    const float* X      = (const float*)d_in[0];
    const float* lcu_w  = (const float*)d_in[1];
    const float* alpha  = (const float*)d_in[2];
    const float* coeff  = (const float*)d_in[3];
    const float* base   = (const float*)d_in[4];
    const float* bias   = (const float*)d_in[5];
    float* out = (float*)d_out;

    init_out<<<(BATCH * NC + 255) / 256, 256, 0, stream>>>(bias, out);
    qkan_kernel<<<(BATCH / RB) * SPLITF, NT, 0, stream>>>(X, lcu_w, alpha, coeff, base, out);
}

// Round 4
// 108.608 us; speedup vs baseline: 1.1596x; 1.1596x over previous
//
#include <hip/hip_runtime.h>

#define BATCH 16384
#define NF    512
#define DEG   8
#define NC    10
#define KB    8

#define SPLITF 8
#define FC     (NF / SPLITF)     // 64 features per block
#define RB     64                // rows per block
#define PITCH  68                // rows 16B-aligned; phase-2 patterns <=2-way banked
#define NT     256               // 4 waves; wave w owns rows [w*16, w*16+16)
#define NWAVES 4

typedef __attribute__((ext_vector_type(8))) short bfrag;   // 8 bf16 (4 VGPRs)
typedef __attribute__((ext_vector_type(4))) float f32x4;   // MFMA C/D

union frag_u { bfrag s; unsigned u[4]; };

__device__ __forceinline__ float fast_tanh(float x) {
    float e = __expf(2.0f * x);
    return 1.0f - 2.0f * __builtin_amdgcn_rcpf(e + 1.0f);
}
__device__ __forceinline__ float fast_sigmoid(float x) {
    return __builtin_amdgcn_rcpf(1.0f + __expf(-x));
}
// round-half-away f32->bf16, two at once: 2 adds + 1 v_perm
__device__ __forceinline__ unsigned bfpack2(float lo, float hi) {
    unsigned ul = __builtin_bit_cast(unsigned, lo) + 0x8000u;
    unsigned uh = __builtin_bit_cast(unsigned, hi) + 0x8000u;
    return __builtin_amdgcn_perm(uh, ul, 0x07060302);
}
// T_1..T_8 of s packed as MFMA A-fragment (element j = T_{j+1})
__device__ __forceinline__ bfrag cheb_frag(float s) {
    float T[KB];
    float tkm1 = 1.0f, tk = s;
    const float s2 = 2.0f * s;
#pragma unroll
    for (int k = 0; k < KB; ++k) {
        T[k] = tk;
        float tn = fmaf(s2, tk, -tkm1);
        tkm1 = tk; tk = tn;
    }
    frag_u f;
#pragma unroll
    for (int i = 0; i < 4; ++i) f.u[i] = bfpack2(T[2 * i], T[2 * i + 1]);
    return f.s;
}

__global__ __launch_bounds__(NT, 6) void qkan_kernel(
    const float* __restrict__ X,        // (B, F)
    const float* __restrict__ lcu_w,    // (F, DEG)
    const float* __restrict__ alpha,    // (F, DEG)
    const float* __restrict__ coeff,    // (C, F, KB)
    const float* __restrict__ base,     // (C, F)
    float* __restrict__ ws)             // (SPLITF, B, NC) partials
{
    __shared__ float s_mem[RB * PITCH];   // 17.4 KB

    const int t      = threadIdx.x;
    const int rowblk = blockIdx.x >> 3;
    const int fsplit = blockIdx.x & (SPLITF - 1);
    const int row0   = rowblk * RB;
    const int fbase  = fsplit * FC;

    // ---------------- phase 1: elementwise -> summed(b,f) into LDS ----------
    {
        const int f2   = t & 31;      // feature pair fA, fA+1
        const int rsub = t >> 5;      // 0..7
        const int fA   = fbase + f2 * 2;

        float w[2][DEG], a[2][DEG], rden[2];   // row-invariant, hoisted
#pragma unroll
        for (int i = 0; i < 2; ++i) {
            const float4 w0 = *(const float4*)(lcu_w + (fA + i) * DEG);
            const float4 w1 = *(const float4*)(lcu_w + (fA + i) * DEG + 4);
            const float4 a0 = *(const float4*)(alpha + (fA + i) * DEG);
            const float4 a1 = *(const float4*)(alpha + (fA + i) * DEG + 4);
            w[i][0]=w0.x; w[i][1]=w0.y; w[i][2]=w0.z; w[i][3]=w0.w;
            w[i][4]=w1.x; w[i][5]=w1.y; w[i][6]=w1.z; w[i][7]=w1.w;
            a[i][0]=a0.x; a[i][1]=a0.y; a[i][2]=a0.z; a[i][3]=a0.w;
            a[i][4]=a1.x; a[i][5]=a1.y; a[i][6]=a1.z; a[i][7]=a1.w;
            float den = 1e-8f;
#pragma unroll
            for (int d = 0; d < DEG; ++d) den += fabsf(w[i][d]);
            rden[i] = __builtin_amdgcn_rcpf(den);
        }

#pragma unroll
        for (int it = 0; it < RB / 8; ++it) {
            const int r = rsub + it * 8;
            const float2 xv = *(const float2*)(X + (row0 + r) * NF + fA);
            float xs[2] = {xv.x, xv.y};
            float sums[2];
#pragma unroll
            for (int i = 0; i < 2; ++i) {
                const float x  = 0.99f * fast_tanh(xs[i]);
                const float x2 = 2.0f * x;
                float tkm1 = 1.0f, tk = x, num = 0.0f;
#pragma unroll
                for (int d = 0; d < DEG; ++d) {
                    num = fmaf(w[i][d], tk, num);
                    float tn = fmaf(x2, tk, -tkm1);
                    tkm1 = tk; tk = tn;
                }
                const float lcu = num * rden[i];
                float ss = 0.0f;
#pragma unroll
                for (int d = 0; d < DEG; ++d)
                    ss += __sinf(lcu * a[i][d]);
                sums[i] = 0.125f * ss;
            }
            *(float2*)(&s_mem[r * PITCH + f2 * 2]) = make_float2(sums[0], sums[1]);
        }
    }
    __syncthreads();

    // ------------- phase 2: MFMA contraction, B-frags streamed --------------
    const int lane = t & 63;
    const int wave = __builtin_amdgcn_readfirstlane(t >> 6);
    const int n    = lane & 15;          // class col
    const int q    = lane >> 4;          // quad
    const bool nv  = (n < NC);
    const int  ncl = nv ? n : (NC - 1);  // clamped: junk stays in cols n>=10,
                                         // which are never stored
    const int rl   = wave * 16 + n;      // this lane's A-row in the tile

    f32x4 acc = {0.f, 0.f, 0.f, 0.f};

    // GEMM1: phi (16 x 512 bf16) @ coeff^T -> 16 K-tiles
#pragma unroll 4
    for (int kt = 0; kt < 16; ++kt) {
        const float* p = coeff + (ncl * NF + fbase + kt * 4 + q) * KB;
        const float4 c0 = *(const float4*)p;
        const float4 c1 = *(const float4*)(p + 4);
        frag_u fb;
        fb.u[0] = bfpack2(c0.x, c0.y); fb.u[1] = bfpack2(c0.z, c0.w);
        fb.u[2] = bfpack2(c1.x, c1.y); fb.u[3] = bfpack2(c1.z, c1.w);

        const float sm = s_mem[rl * PITCH + kt * 4 + q];
        const bfrag av = cheb_frag(0.99f * fast_tanh(sm));
        acc = __builtin_amdgcn_mfma_f32_16x16x32_bf16(av, fb.s, acc, 0, 0, 0);
    }

    // GEMM2: silu (16 x 64 bf16) @ base^T -> 2 K-tiles
#pragma unroll
    for (int kt2 = 0; kt2 < 2; ++kt2) {
        const float* p = base + ncl * NF + fbase + kt2 * 32 + q * 8;
        const float4 b0 = *(const float4*)p;
        const float4 b1 = *(const float4*)(p + 4);
        frag_u fb;
        fb.u[0] = bfpack2(b0.x, b0.y); fb.u[1] = bfpack2(b0.z, b0.w);
        fb.u[2] = bfpack2(b1.x, b1.y); fb.u[3] = bfpack2(b1.z, b1.w);

        const int off = kt2 * 32 + q * 8;
        const float4 v0 = *(const float4*)(&s_mem[rl * PITCH + off]);
        const float4 v1 = *(const float4*)(&s_mem[rl * PITCH + off + 4]);
        float v[8] = {v0.x, v0.y, v0.z, v0.w, v1.x, v1.y, v1.z, v1.w};
        float sl[8];
#pragma unroll
        for (int j = 0; j < 8; ++j)
            sl[j] = v[j] * fast_sigmoid(v[j]);
        frag_u fa;
        fa.u[0] = bfpack2(sl[0], sl[1]); fa.u[1] = bfpack2(sl[2], sl[3]);
        fa.u[2] = bfpack2(sl[4], sl[5]); fa.u[3] = bfpack2(sl[6], sl[7]);
        acc = __builtin_amdgcn_mfma_f32_16x16x32_bf16(fa.s, fb.s, acc, 0, 0, 0);
    }

    // ------------- epilogue: partial store, no atomics ----------------------
    // D layout: row = q*4+i, col = n.
    if (nv) {
        float* wsp = ws + (size_t)fsplit * (BATCH * NC);
#pragma unroll
        for (int i = 0; i < 4; ++i)
            wsp[(row0 + wave * 16 + q * 4 + i) * NC + n] = acc[i];
    }
}

// out[b][c] = bias[c] + sum over 8 feature-split partials
__global__ __launch_bounds__(256) void reduce_kernel(
    const float* __restrict__ ws, const float* __restrict__ bias,
    float* __restrict__ out)
{
    const int idx = blockIdx.x * 256 + threadIdx.x;
    if (idx < BATCH * NC) {
        const int c = idx % NC;
        float v = bias[c];
#pragma unroll
        for (int s = 0; s < SPLITF; ++s)
            v += ws[(size_t)s * (BATCH * NC) + idx];
        out[idx] = v;
    }
}

extern "C" void kernel_launch(void* const* d_in, const int* in_sizes, int n_in,
                              void* d_out, int out_size, void* d_ws, size_t ws_size,
                              hipStream_t stream) {
    const float* X      = (const float*)d_in[0];
    const float* lcu_w  = (const float*)d_in[1];
    const float* alpha  = (const float*)d_in[2];
    const float* coeff  = (const float*)d_in[3];
    const float* base   = (const float*)d_in[4];
    const float* bias   = (const float*)d_in[5];
    float* out = (float*)d_out;
    float* ws  = (float*)d_ws;   // needs SPLITF*B*NC*4 = 5.24 MB

    qkan_kernel<<<(BATCH / RB) * SPLITF, NT, 0, stream>>>(X, lcu_w, alpha, coeff, base, ws);
    reduce_kernel<<<(BATCH * NC + 255) / 256, 256, 0, stream>>>(ws, bias, out);
}

// Round 5
// 100.373 us; speedup vs baseline: 1.2547x; 1.0821x over previous
//
#include <hip/hip_runtime.h>

#define BATCH 16384
#define NF    512
#define DEG   8
#define NC    10
#define KB    8

#define SPLITF 8
#define FC     (NF / SPLITF)     // 64 features per block
#define RB     64                // rows per block
#define PITCH  68                // rows 16B-aligned; phase-2 patterns <=2-way banked
#define NT     256               // 4 waves; wave w owns rows [w*16, w*16+16)

#define CBN (NC * NF * KB)       // 40960 packed coeff elems
#define BBN (NC * NF)            // 5120 packed base elems
#define WS_PART (SPLITF * BATCH * NC)   // float slots before packed tables

#define INV2PI 0.15915494309189535f
#define LOG2E  1.4426950408889634f

typedef __attribute__((ext_vector_type(2))) float v2f;     // -> v_pk_*_f32
typedef __attribute__((ext_vector_type(8))) short bfrag;   // 8 bf16 (4 VGPRs)
typedef __attribute__((ext_vector_type(4))) float f32x4;   // MFMA C/D

union frag_u { bfrag s; unsigned u[4]; };

__device__ __forceinline__ v2f v2fma(v2f a, v2f b, v2f c) {
    return __builtin_elementwise_fma(a, b, c);
}
__device__ __forceinline__ v2f v2exp(v2f x) {              // e^x
    v2f a = x * LOG2E;
    v2f r; r.x = __builtin_amdgcn_exp2f(a.x); r.y = __builtin_amdgcn_exp2f(a.y);
    return r;
}
__device__ __forceinline__ v2f v2rcp(v2f x) {
    v2f r; r.x = __builtin_amdgcn_rcpf(x.x); r.y = __builtin_amdgcn_rcpf(x.y);
    return r;
}
__device__ __forceinline__ v2f v2sin2pi(v2f x) {           // sin(2*pi*x)
    v2f r; r.x = __builtin_amdgcn_sinf(x.x); r.y = __builtin_amdgcn_sinf(x.y);
    return r;
}
// 0.99*tanh(x) = 0.99 - 1.98/(exp(2x)+1)
__device__ __forceinline__ v2f v2tanh99(v2f x) {
    v2f e = v2exp(x + x);
    v2f r = v2rcp(e + 1.0f);
    return v2fma(r, (v2f)(-1.98f), (v2f)(0.99f));
}
// silu(v) = v / (1 + exp(-v)), packed
__device__ __forceinline__ v2f v2silu(v2f v) {
    v2f e = v2exp(-v);
    v2f r = v2rcp(e + 1.0f);
    return v * r;
}
// round-half-up f32->bf16 pair: {hi[31:16], lo[31:16]}
__device__ __forceinline__ unsigned bfpack2(float lo, float hi) {
    unsigned ul = __builtin_bit_cast(unsigned, lo) + 0x8000u;
    unsigned uh = __builtin_bit_cast(unsigned, hi) + 0x8000u;
    return __builtin_amdgcn_perm(uh, ul, 0x07060302);
}

// ---- prep: bf16-pack coeff (CBN) + base (BBN) into ws tail, every launch ----
__global__ __launch_bounds__(256) void prep_kernel(
    const float* __restrict__ coeff, const float* __restrict__ base,
    unsigned short* __restrict__ pk)
{
    const int i = blockIdx.x * 256 + threadIdx.x;
    if (i < CBN)
        pk[i] = (unsigned short)((__builtin_bit_cast(unsigned, coeff[i]) + 0x8000u) >> 16);
    else if (i < CBN + BBN)
        pk[i] = (unsigned short)((__builtin_bit_cast(unsigned, base[i - CBN]) + 0x8000u) >> 16);
}

__global__ __launch_bounds__(NT, 6) void qkan_kernel(
    const float* __restrict__ X,        // (B, F)
    const float* __restrict__ lcu_w,    // (F, DEG)
    const float* __restrict__ alpha,    // (F, DEG)
    const unsigned short* __restrict__ pk,  // bf16: coeff[CBN] then base[BBN]
    float* __restrict__ ws)             // (SPLITF, B, NC) partials
{
    __shared__ float s_mem[RB * PITCH];   // 17.4 KB

    const int t      = threadIdx.x;
    const int rowblk = blockIdx.x >> 3;
    const int fsplit = blockIdx.x & (SPLITF - 1);
    const int row0   = rowblk * RB;
    const int fbase  = fsplit * FC;

    // ---------------- phase 1: elementwise -> summed(b,f) into LDS ----------
    {
        const int f2   = t & 31;      // feature pair fA, fA+1
        const int rsub = t >> 5;      // 0..7
        const int fA   = fbase + f2 * 2;

        // Row-invariant tables, packed across the 2 features.
        float wa[2][DEG], aa[2][DEG], den[2];
#pragma unroll
        for (int i = 0; i < 2; ++i) {
            const float4 w0 = *(const float4*)(lcu_w + (fA + i) * DEG);
            const float4 w1 = *(const float4*)(lcu_w + (fA + i) * DEG + 4);
            const float4 a0 = *(const float4*)(alpha + (fA + i) * DEG);
            const float4 a1 = *(const float4*)(alpha + (fA + i) * DEG + 4);
            wa[i][0]=w0.x; wa[i][1]=w0.y; wa[i][2]=w0.z; wa[i][3]=w0.w;
            wa[i][4]=w1.x; wa[i][5]=w1.y; wa[i][6]=w1.z; wa[i][7]=w1.w;
            aa[i][0]=a0.x; aa[i][1]=a0.y; aa[i][2]=a0.z; aa[i][3]=a0.w;
            aa[i][4]=a1.x; aa[i][5]=a1.y; aa[i][6]=a1.z; aa[i][7]=a1.w;
            float d = 1e-8f;
#pragma unroll
            for (int k = 0; k < DEG; ++k) d += fabsf(wa[i][k]);
            den[i] = d;
        }
        v2f W[DEG], A2[DEG];
#pragma unroll
        for (int d = 0; d < DEG; ++d) {
            W[d]  = (v2f){wa[0][d], wa[1][d]};
            A2[d] = (v2f){aa[0][d] * INV2PI, aa[1][d] * INV2PI};  // fold 1/2pi
        }
        const v2f rden = (v2f){__builtin_amdgcn_rcpf(den[0]),
                               __builtin_amdgcn_rcpf(den[1])};

#pragma unroll
        for (int it = 0; it < RB / 8; ++it) {
            const int r = rsub + it * 8;
            const v2f xv = *(const v2f*)(X + (row0 + r) * NF + fA);
            const v2f x  = v2tanh99(xv);
            const v2f x2 = x + x;
            v2f tkm1 = (v2f){1.0f, 1.0f}, tk = x, num = (v2f){0.0f, 0.0f};
#pragma unroll
            for (int d = 0; d < DEG; ++d) {
                num = v2fma(W[d], tk, num);
                v2f tn = v2fma(x2, tk, -tkm1);
                tkm1 = tk; tk = tn;
            }
            const v2f lcu = num * rden;
            v2f ss = (v2f){0.0f, 0.0f};
#pragma unroll
            for (int d = 0; d < DEG; ++d)
                ss += v2sin2pi(lcu * A2[d]);
            *(v2f*)(&s_mem[r * PITCH + f2 * 2]) = ss * 0.125f;
        }
    }
    __syncthreads();

    // ------------- phase 2: MFMA contraction, prepacked bf16 B --------------
    const int lane = t & 63;
    const int wave = __builtin_amdgcn_readfirstlane(t >> 6);
    const int n    = lane & 15;          // class col
    const int q    = lane >> 4;          // quad
    const bool nv  = (n < NC);
    const int  ncl = nv ? n : (NC - 1);  // junk stays in cols n>=10 (not stored)
    const int rl   = wave * 16 + n;      // this lane's A-row in the tile

    const unsigned short* cb = pk;                         // coeff bf16
    const unsigned short* bb = pk + CBN;                   // base  bf16
    const unsigned short* cbase = cb + (ncl * NF + fbase) * KB;

    f32x4 acc0 = {0.f, 0.f, 0.f, 0.f};
    f32x4 acc1 = {0.f, 0.f, 0.f, 0.f};

    // GEMM1: 16 K-tiles, processed in pairs (packed tanh/cheb, 2 accs)
#pragma unroll 4
    for (int kp = 0; kp < 8; ++kp) {
        const bfrag b0 = *(const bfrag*)(cbase + (kp * 8 + q) * KB);
        const bfrag b1 = *(const bfrag*)(cbase + (kp * 8 + 4 + q) * KB);

        const float sA = s_mem[rl * PITCH + kp * 8 + q];
        const float sB = s_mem[rl * PITCH + kp * 8 + 4 + q];
        const v2f s  = v2tanh99((v2f){sA, sB});
        const v2f s2 = s + s;
        v2f T[KB];
        {
            v2f tkm1 = (v2f){1.0f, 1.0f}, tk = s;
#pragma unroll
            for (int k = 0; k < KB; ++k) {
                T[k] = tk;
                v2f tn = v2fma(s2, tk, -tkm1);
                tkm1 = tk; tk = tn;
            }
        }
        frag_u fa0, fa1;
#pragma unroll
        for (int i = 0; i < 4; ++i) {
            fa0.u[i] = bfpack2(T[2 * i].x, T[2 * i + 1].x);
            fa1.u[i] = bfpack2(T[2 * i].y, T[2 * i + 1].y);
        }
        acc0 = __builtin_amdgcn_mfma_f32_16x16x32_bf16(fa0.s, b0, acc0, 0, 0, 0);
        acc1 = __builtin_amdgcn_mfma_f32_16x16x32_bf16(fa1.s, b1, acc1, 0, 0, 0);
    }

    // GEMM2: silu branch, 2 K-tiles
#pragma unroll
    for (int kt2 = 0; kt2 < 2; ++kt2) {
        const bfrag b = *(const bfrag*)(bb + ncl * NF + fbase + kt2 * 32 + q * 8);
        const int off = kt2 * 32 + q * 8;
        const float4 v0 = *(const float4*)(&s_mem[rl * PITCH + off]);
        const float4 v1 = *(const float4*)(&s_mem[rl * PITCH + off + 4]);
        v2f vv[4] = {{v0.x, v0.y}, {v0.z, v0.w}, {v1.x, v1.y}, {v1.z, v1.w}};
        frag_u fa;
#pragma unroll
        for (int g = 0; g < 4; ++g) {
            const v2f sl = v2silu(vv[g]);
            fa.u[g] = bfpack2(sl.x, sl.y);
        }
        acc0 = __builtin_amdgcn_mfma_f32_16x16x32_bf16(fa.s, b, acc0, 0, 0, 0);
    }

    // ------------- epilogue: partial store, no atomics ----------------------
    if (nv) {
        const f32x4 acc = acc0 + acc1;
        float* wsp = ws + (size_t)fsplit * (BATCH * NC);
#pragma unroll
        for (int i = 0; i < 4; ++i)
            wsp[(row0 + wave * 16 + q * 4 + i) * NC + n] = acc[i];
    }
}

// out[b][c] = bias[c] + sum over 8 feature-split partials
__global__ __launch_bounds__(256) void reduce_kernel(
    const float* __restrict__ ws, const float* __restrict__ bias,
    float* __restrict__ out)
{
    const int idx = blockIdx.x * 256 + threadIdx.x;
    if (idx < BATCH * NC) {
        const int c = idx % NC;
        float v = bias[c];
#pragma unroll
        for (int s = 0; s < SPLITF; ++s)
            v += ws[(size_t)s * (BATCH * NC) + idx];
        out[idx] = v;
    }
}

extern "C" void kernel_launch(void* const* d_in, const int* in_sizes, int n_in,
                              void* d_out, int out_size, void* d_ws, size_t ws_size,
                              hipStream_t stream) {
    const float* X      = (const float*)d_in[0];
    const float* lcu_w  = (const float*)d_in[1];
    const float* alpha  = (const float*)d_in[2];
    const float* coeff  = (const float*)d_in[3];
    const float* base   = (const float*)d_in[4];
    const float* bias   = (const float*)d_in[5];
    float* out = (float*)d_out;
    float* ws  = (float*)d_ws;                      // partials: 5.24 MB
    unsigned short* pk = (unsigned short*)(ws + WS_PART);  // +92 KB bf16 tables

    prep_kernel<<<(CBN + BBN + 255) / 256, 256, 0, stream>>>(coeff, base, pk);
    qkan_kernel<<<(BATCH / RB) * SPLITF, NT, 0, stream>>>(X, lcu_w, alpha, pk, ws);
    reduce_kernel<<<(BATCH * NC + 255) / 256, 256, 0, stream>>>(ws, bias, out);
}

// Round 7
// 99.844 us; speedup vs baseline: 1.2614x; 1.0053x over previous
//
#include <hip/hip_runtime.h>
#include <hip/hip_bf16.h>

#define BATCH 16384
#define NF    512
#define DEG   8
#define NC    10
#define KB    8

#define RB    16                 // rows per block; block owns ALL 512 features
#define PITCH (NF + 4)           // 516: rows 16B-aligned, bank phase 4
#define NT    256                // 4 waves; wave w owns features [w*128, w*128+128)

#define CBN (NC * NF * KB)       // 40960 packed coeff elems
#define BBN (NC * NF)            // 5120 packed base elems

#define INV2PI 0.15915494309189535f
#define LOG2E  1.4426950408889634f

typedef __attribute__((ext_vector_type(2))) float v2f;     // -> v_pk_*_f32
typedef __attribute__((ext_vector_type(8))) short bfrag;   // 8 bf16 (4 VGPRs)
typedef __attribute__((ext_vector_type(4))) float f32x4;   // MFMA C/D

union frag_u { bfrag s; unsigned u[4]; };

__device__ __forceinline__ v2f v2fma(v2f a, v2f b, v2f c) {
    return __builtin_elementwise_fma(a, b, c);
}
__device__ __forceinline__ v2f v2exp(v2f x) {              // e^x
    v2f a = x * LOG2E;
    v2f r; r.x = __builtin_amdgcn_exp2f(a.x); r.y = __builtin_amdgcn_exp2f(a.y);
    return r;
}
__device__ __forceinline__ v2f v2rcp(v2f x) {
    v2f r; r.x = __builtin_amdgcn_rcpf(x.x); r.y = __builtin_amdgcn_rcpf(x.y);
    return r;
}
__device__ __forceinline__ v2f v2sin2pi(v2f x) {           // sin(2*pi*x)
    v2f r; r.x = __builtin_amdgcn_sinf(x.x); r.y = __builtin_amdgcn_sinf(x.y);
    return r;
}
// 0.99*tanh(x) = 0.99 - 1.98/(exp(2x)+1)
__device__ __forceinline__ v2f v2tanh99(v2f x) {
    v2f e = v2exp(x + x);
    v2f r = v2rcp(e + 1.0f);
    return v2fma(r, (v2f)(-1.98f), (v2f)(0.99f));
}
// silu(v) = v / (1 + exp(-v)), packed
__device__ __forceinline__ v2f v2silu(v2f v) {
    v2f e = v2exp(-v);
    v2f r = v2rcp(e + 1.0f);
    return v * r;
}
// f32 pair -> packed bf16 via v_cvt_pk_bf16_f32 (lo in low 16 bits)
__device__ __forceinline__ unsigned cvtpk2(float lo, float hi) {
    __hip_bfloat162 h = __float22bfloat162_rn(float2{lo, hi});
    unsigned u;
    __builtin_memcpy(&u, &h, sizeof(u));
    return u;
}

// ---- prep: bf16-pack coeff (CBN) + base (BBN) into ws, every launch --------
__global__ __launch_bounds__(256) void prep_kernel(
    const float* __restrict__ coeff, const float* __restrict__ base,
    unsigned short* __restrict__ pk)
{
    const int i = blockIdx.x * 256 + threadIdx.x;
    if (i < CBN)
        pk[i] = (unsigned short)((__builtin_bit_cast(unsigned, coeff[i]) + 0x8000u) >> 16);
    else if (i < CBN + BBN)
        pk[i] = (unsigned short)((__builtin_bit_cast(unsigned, base[i - CBN]) + 0x8000u) >> 16);
}

__global__ __launch_bounds__(NT, 4) void qkan_kernel(
    const float* __restrict__ X,        // (B, F)
    const float* __restrict__ lcu_w,    // (F, DEG)
    const float* __restrict__ alpha,    // (F, DEG)
    const unsigned short* __restrict__ pk,  // bf16: coeff[CBN] then base[BBN]
    const float* __restrict__ bias,     // (C)
    float* __restrict__ out)            // (B, C)
{
    __shared__ float s_mem[RB * PITCH];         // 33 KB: summed(b,f) tile
    __shared__ float s_red[4 * RB * 16];        // 4 KB: cross-wave partials

    const int t    = threadIdx.x;
    const int row0 = blockIdx.x * RB;

    // ---------------- phase 1: elementwise -> summed(b,f) into LDS ----------
    {
        const int fA = t * 2;        // this thread's feature pair, all rows

        float wa[2][DEG], aa[2][DEG], den[2];
#pragma unroll
        for (int i = 0; i < 2; ++i) {
            const float4 w0 = *(const float4*)(lcu_w + (fA + i) * DEG);
            const float4 w1 = *(const float4*)(lcu_w + (fA + i) * DEG + 4);
            const float4 a0 = *(const float4*)(alpha + (fA + i) * DEG);
            const float4 a1 = *(const float4*)(alpha + (fA + i) * DEG + 4);
            wa[i][0]=w0.x; wa[i][1]=w0.y; wa[i][2]=w0.z; wa[i][3]=w0.w;
            wa[i][4]=w1.x; wa[i][5]=w1.y; wa[i][6]=w1.z; wa[i][7]=w1.w;
            aa[i][0]=a0.x; aa[i][1]=a0.y; aa[i][2]=a0.z; aa[i][3]=a0.w;
            aa[i][4]=a1.x; aa[i][5]=a1.y; aa[i][6]=a1.z; aa[i][7]=a1.w;
            float d = 1e-8f;
#pragma unroll
            for (int k = 0; k < DEG; ++k) d += fabsf(wa[i][k]);
            den[i] = d;
        }
        v2f W[DEG], A2[DEG];
#pragma unroll
        for (int d = 0; d < DEG; ++d) {
            W[d]  = (v2f){wa[0][d], wa[1][d]};
            A2[d] = (v2f){aa[0][d] * INV2PI, aa[1][d] * INV2PI};  // fold 1/2pi
        }
        const v2f rden = (v2f){__builtin_amdgcn_rcpf(den[0]),
                               __builtin_amdgcn_rcpf(den[1])};

#pragma unroll 4
        for (int r = 0; r < RB; ++r) {
            const v2f xv = *(const v2f*)(X + (row0 + r) * NF + fA);
            const v2f x  = v2tanh99(xv);
            const v2f x2 = x + x;
            v2f tkm1 = (v2f){1.0f, 1.0f}, tk = x, num = (v2f){0.0f, 0.0f};
#pragma unroll
            for (int d = 0; d < DEG; ++d) {
                num = v2fma(W[d], tk, num);
                v2f tn = v2fma(x2, tk, -tkm1);
                tkm1 = tk; tk = tn;
            }
            const v2f lcu = num * rden;
            v2f ss = (v2f){0.0f, 0.0f};
#pragma unroll
            for (int d = 0; d < DEG; ++d)
                ss += v2sin2pi(lcu * A2[d]);
            *(v2f*)(&s_mem[r * PITCH + fA]) = ss * 0.125f;
        }
    }
    __syncthreads();

    // ------------- phase 2: MFMA contraction; waves split K -----------------
    const int lane = t & 63;
    const int wave = __builtin_amdgcn_readfirstlane(t >> 6);
    const int n    = lane & 15;          // class col (and A-row m)
    const int q    = lane >> 4;          // quad
    const int ncl  = (n < NC) ? n : (NC - 1);  // junk cols n>=10 never read back
    const int fw   = wave * 128;         // this wave's feature range

    const unsigned short* cb = pk;                          // coeff bf16
    const unsigned short* bb = pk + CBN;                    // base  bf16
    const unsigned short* cbase = cb + (ncl * NF + fw) * KB;

    f32x4 acc0 = {0.f, 0.f, 0.f, 0.f};
    f32x4 acc1 = {0.f, 0.f, 0.f, 0.f};

    // GEMM1: phi @ coeff^T over 128 features = 32 K-tiles, in pairs
#pragma unroll 4
    for (int kp = 0; kp < 16; ++kp) {
        const bfrag b0 = *(const bfrag*)(cbase + (kp * 8 + q) * KB);
        const bfrag b1 = *(const bfrag*)(cbase + (kp * 8 + 4 + q) * KB);

        const float sA = s_mem[n * PITCH + fw + kp * 8 + q];
        const float sB = s_mem[n * PITCH + fw + kp * 8 + 4 + q];
        const v2f s  = v2tanh99((v2f){sA, sB});
        const v2f s2 = s + s;
        v2f T[KB];
        {
            v2f tkm1 = (v2f){1.0f, 1.0f}, tk = s;
#pragma unroll
            for (int k = 0; k < KB; ++k) {
                T[k] = tk;
                v2f tn = v2fma(s2, tk, -tkm1);
                tkm1 = tk; tk = tn;
            }
        }
        frag_u fa0, fa1;
#pragma unroll
        for (int i = 0; i < 4; ++i) {
            fa0.u[i] = cvtpk2(T[2 * i].x, T[2 * i + 1].x);
            fa1.u[i] = cvtpk2(T[2 * i].y, T[2 * i + 1].y);
        }
        acc0 = __builtin_amdgcn_mfma_f32_16x16x32_bf16(fa0.s, b0, acc0, 0, 0, 0);
        acc1 = __builtin_amdgcn_mfma_f32_16x16x32_bf16(fa1.s, b1, acc1, 0, 0, 0);
    }

    // GEMM2: silu @ base^T over 128 features = 4 K-tiles
#pragma unroll
    for (int kt2 = 0; kt2 < 4; ++kt2) {
        const bfrag b = *(const bfrag*)(bb + ncl * NF + fw + kt2 * 32 + q * 8);
        const int off = n * PITCH + fw + kt2 * 32 + q * 8;
        const float4 v0 = *(const float4*)(&s_mem[off]);
        const float4 v1 = *(const float4*)(&s_mem[off + 4]);
        v2f vv[4] = {{v0.x, v0.y}, {v0.z, v0.w}, {v1.x, v1.y}, {v1.z, v1.w}};
        frag_u fa;
#pragma unroll
        for (int g = 0; g < 4; ++g) {
            const v2f sl = v2silu(vv[g]);
            fa.u[g] = cvtpk2(sl.x, sl.y);
        }
        if (kt2 & 1)
            acc1 = __builtin_amdgcn_mfma_f32_16x16x32_bf16(fa.s, b, acc1, 0, 0, 0);
        else
            acc0 = __builtin_amdgcn_mfma_f32_16x16x32_bf16(fa.s, b, acc0, 0, 0, 0);
    }

    // ------------- cross-wave K-reduction + store ---------------------------
    // D layout: row = q*4+i, col = n. Write all 16 cols; only c<10 read back.
    const f32x4 acc = acc0 + acc1;
#pragma unroll
    for (int i = 0; i < 4; ++i)
        s_red[(wave * RB + q * 4 + i) * 16 + n] = acc[i];
    __syncthreads();

    if (t < RB * NC) {
        const int r = t / NC;
        const int c = t - r * NC;
        float v = bias[c];
#pragma unroll
        for (int w = 0; w < 4; ++w)
            v += s_red[(w * RB + r) * 16 + c];
        out[(row0 + r) * NC + c] = v;
    }
}

extern "C" void kernel_launch(void* const* d_in, const int* in_sizes, int n_in,
                              void* d_out, int out_size, void* d_ws, size_t ws_size,
                              hipStream_t stream) {
    const float* X      = (const float*)d_in[0];
    const float* lcu_w  = (const float*)d_in[1];
    const float* alpha  = (const float*)d_in[2];
    const float* coeff  = (const float*)d_in[3];
    const float* base   = (const float*)d_in[4];
    const float* bias   = (const float*)d_in[5];
    float* out = (float*)d_out;
    unsigned short* pk = (unsigned short*)d_ws;   // 92 KB bf16 tables

    prep_kernel<<<(CBN + BBN + 255) / 256, 256, 0, stream>>>(coeff, base, pk);
    qkan_kernel<<<BATCH / RB, NT, 0, stream>>>(X, lcu_w, alpha, pk, bias, out);
}